// Round 1
// baseline (6915.563 us; speedup 1.0000x reference)
//
#include <hip/hip_runtime.h>

#define NN 100000
#define EE 300000
#define GG 4000
#define LL 5

// ---------------- embed: h = relu(x @ embW + embB) ----------------
__global__ __launch_bounds__(256) void k_embed(
    float* __restrict__ h, const float* __restrict__ x,
    const float* __restrict__ embW, const float* __restrict__ embB)
{
    int n = blockIdx.x;
    int t = threadIdx.x;
    float acc = embB[t];
#pragma unroll
    for (int k = 0; k < 40; ++k)
        acc = fmaf(x[n * 40 + k], embW[k * 256 + t], acc);
    h[n * 256 + t] = fmaxf(acc, 0.f);
}

// ---------------- agg = h + ee1[l][4] + ee2[l][0] ----------------
__global__ __launch_bounds__(256) void k_init_agg(
    float4* __restrict__ agg, const float4* __restrict__ h,
    const float* __restrict__ ee1l, const float* __restrict__ ee2l)
{
    int idx = blockIdx.x * 256 + threadIdx.x;   // total N*64 float4s
    int d4 = idx & 63;
    const float* c1 = ee1l + 4 * 256;
    const float* c2 = ee2l;
    float4 hv = h[idx];
    float4 o;
    o.x = hv.x + c1[d4 * 4 + 0] + c2[d4 * 4 + 0];
    o.y = hv.y + c1[d4 * 4 + 1] + c2[d4 * 4 + 1];
    o.z = hv.z + c1[d4 * 4 + 2] + c2[d4 * 4 + 2];
    o.w = hv.w + c1[d4 * 4 + 3] + c2[d4 * 4 + 3];
    agg[idx] = o;
}

// ---------------- edge scatter: agg[dst] += h[src] + ee1[ea0] + ee2[ea1] ----
__global__ __launch_bounds__(256) void k_scatter(
    float* agg, const float* __restrict__ h,
    const int* __restrict__ edge_index, const int* __restrict__ edge_attr,
    const float* __restrict__ ee1l, const float* __restrict__ ee2l)
{
    int e = blockIdx.x;
    int t = threadIdx.x;
    int s  = edge_index[e];
    int d  = edge_index[EE + e];
    int a0 = edge_attr[2 * e];
    int a1 = edge_attr[2 * e + 1];
    float v = h[s * 256 + t] + ee1l[a0 * 256 + t] + ee2l[a1 * 256 + t];
    atomicAdd(&agg[d * 256 + t], v);
}

// ---------------- fused: h2 = relu(agg@W1+b1)@W2+b2, + BN partial stats ----
// 32 rows per block, 256 threads: (rg = t>>5 in [0,8), cg = t&31 in [0,32))
// thread owns rows rg*4..rg*4+3.
__global__ __launch_bounds__(256, 2) void k_fused_mlp(
    float* h2, const float* agg,
    const float* __restrict__ W1, const float* __restrict__ b1,
    const float* __restrict__ W2, const float* __restrict__ b2,
    float* __restrict__ stats)
{
    __shared__ float smem[18560];          // 74240 B -> 2 blocks/CU
    float* A   = smem;                     // [32][260]  = 8320 floats
    float* W1t = smem + 8320;              // [16][512]  = 8192 floats
    float* U   = smem;                     // [32][516]  = 16512 floats (overlay)
    float* W2t = smem + 16512;             // [8][256]   = 2048 floats
    float* C   = smem;                     // [32][264]  = 8448 floats (overlay)

    const int t  = threadIdx.x;
    const int rg = t >> 5;
    const int cg = t & 31;
    const int n0 = blockIdx.x * 32;

    // load A tile (coalesced), padded stride 260
#pragma unroll
    for (int i = 0; i < 32; ++i) {
        int lin = i * 256 + t;
        A[(lin >> 8) * 260 + (lin & 255)] = agg[n0 * 256 + lin];
    }
    __syncthreads();

    // ---- stage 1: U = relu(A @ W1 + b1), thread cols c = cg*4 + 128*u ----
    float acc1[4][16];
#pragma unroll
    for (int i = 0; i < 4; ++i)
#pragma unroll
        for (int j = 0; j < 16; ++j) acc1[i][j] = 0.f;

    for (int k0 = 0; k0 < 256; k0 += 16) {
#pragma unroll
        for (int i = 0; i < 32; ++i) {
            int lin = i * 256 + t;
            W1t[lin] = W1[k0 * 512 + lin];
        }
        __syncthreads();
#pragma unroll
        for (int kk = 0; kk < 16; ++kk) {
            float a0 = A[(rg * 4 + 0) * 260 + k0 + kk];
            float a1 = A[(rg * 4 + 1) * 260 + k0 + kk];
            float a2 = A[(rg * 4 + 2) * 260 + k0 + kk];
            float a3 = A[(rg * 4 + 3) * 260 + k0 + kk];
#pragma unroll
            for (int u = 0; u < 4; ++u) {
                float4 w = *(const float4*)&W1t[kk * 512 + cg * 4 + 128 * u];
                acc1[0][u * 4 + 0] = fmaf(a0, w.x, acc1[0][u * 4 + 0]);
                acc1[0][u * 4 + 1] = fmaf(a0, w.y, acc1[0][u * 4 + 1]);
                acc1[0][u * 4 + 2] = fmaf(a0, w.z, acc1[0][u * 4 + 2]);
                acc1[0][u * 4 + 3] = fmaf(a0, w.w, acc1[0][u * 4 + 3]);
                acc1[1][u * 4 + 0] = fmaf(a1, w.x, acc1[1][u * 4 + 0]);
                acc1[1][u * 4 + 1] = fmaf(a1, w.y, acc1[1][u * 4 + 1]);
                acc1[1][u * 4 + 2] = fmaf(a1, w.z, acc1[1][u * 4 + 2]);
                acc1[1][u * 4 + 3] = fmaf(a1, w.w, acc1[1][u * 4 + 3]);
                acc1[2][u * 4 + 0] = fmaf(a2, w.x, acc1[2][u * 4 + 0]);
                acc1[2][u * 4 + 1] = fmaf(a2, w.y, acc1[2][u * 4 + 1]);
                acc1[2][u * 4 + 2] = fmaf(a2, w.z, acc1[2][u * 4 + 2]);
                acc1[2][u * 4 + 3] = fmaf(a2, w.w, acc1[2][u * 4 + 3]);
                acc1[3][u * 4 + 0] = fmaf(a3, w.x, acc1[3][u * 4 + 0]);
                acc1[3][u * 4 + 1] = fmaf(a3, w.y, acc1[3][u * 4 + 1]);
                acc1[3][u * 4 + 2] = fmaf(a3, w.z, acc1[3][u * 4 + 2]);
                acc1[3][u * 4 + 3] = fmaf(a3, w.w, acc1[3][u * 4 + 3]);
            }
        }
        __syncthreads();
    }

    // write U = relu(acc1 + b1) into LDS (overlays A/W1t; all reads done)
#pragma unroll
    for (int i = 0; i < 4; ++i) {
#pragma unroll
        for (int u = 0; u < 4; ++u) {
            int c = cg * 4 + 128 * u;
            float4 bv = *(const float4*)&b1[c];
            float4 w;
            w.x = fmaxf(acc1[i][u * 4 + 0] + bv.x, 0.f);
            w.y = fmaxf(acc1[i][u * 4 + 1] + bv.y, 0.f);
            w.z = fmaxf(acc1[i][u * 4 + 2] + bv.z, 0.f);
            w.w = fmaxf(acc1[i][u * 4 + 3] + bv.w, 0.f);
            *(float4*)&U[(rg * 4 + i) * 516 + c] = w;
        }
    }
    __syncthreads();

    // ---- stage 2: C = U @ W2 + b2, thread cols c = cg*4 + 128*u (u<2) ----
    float acc2[4][8];
#pragma unroll
    for (int i = 0; i < 4; ++i)
#pragma unroll
        for (int j = 0; j < 8; ++j) acc2[i][j] = 0.f;

    for (int k0 = 0; k0 < 512; k0 += 8) {
#pragma unroll
        for (int i = 0; i < 8; ++i) {
            int lin = i * 256 + t;
            W2t[lin] = W2[k0 * 256 + lin];
        }
        __syncthreads();
#pragma unroll
        for (int kk = 0; kk < 8; ++kk) {
            float u0 = U[(rg * 4 + 0) * 516 + k0 + kk];
            float u1 = U[(rg * 4 + 1) * 516 + k0 + kk];
            float u2 = U[(rg * 4 + 2) * 516 + k0 + kk];
            float u3 = U[(rg * 4 + 3) * 516 + k0 + kk];
#pragma unroll
            for (int u = 0; u < 2; ++u) {
                float4 w = *(const float4*)&W2t[kk * 256 + cg * 4 + 128 * u];
                acc2[0][u * 4 + 0] = fmaf(u0, w.x, acc2[0][u * 4 + 0]);
                acc2[0][u * 4 + 1] = fmaf(u0, w.y, acc2[0][u * 4 + 1]);
                acc2[0][u * 4 + 2] = fmaf(u0, w.z, acc2[0][u * 4 + 2]);
                acc2[0][u * 4 + 3] = fmaf(u0, w.w, acc2[0][u * 4 + 3]);
                acc2[1][u * 4 + 0] = fmaf(u1, w.x, acc2[1][u * 4 + 0]);
                acc2[1][u * 4 + 1] = fmaf(u1, w.y, acc2[1][u * 4 + 1]);
                acc2[1][u * 4 + 2] = fmaf(u1, w.z, acc2[1][u * 4 + 2]);
                acc2[1][u * 4 + 3] = fmaf(u1, w.w, acc2[1][u * 4 + 3]);
                acc2[2][u * 4 + 0] = fmaf(u2, w.x, acc2[2][u * 4 + 0]);
                acc2[2][u * 4 + 1] = fmaf(u2, w.y, acc2[2][u * 4 + 1]);
                acc2[2][u * 4 + 2] = fmaf(u2, w.z, acc2[2][u * 4 + 2]);
                acc2[2][u * 4 + 3] = fmaf(u2, w.w, acc2[2][u * 4 + 3]);
                acc2[3][u * 4 + 0] = fmaf(u3, w.x, acc2[3][u * 4 + 0]);
                acc2[3][u * 4 + 1] = fmaf(u3, w.y, acc2[3][u * 4 + 1]);
                acc2[3][u * 4 + 2] = fmaf(u3, w.z, acc2[3][u * 4 + 2]);
                acc2[3][u * 4 + 3] = fmaf(u3, w.w, acc2[3][u * 4 + 3]);
            }
        }
        __syncthreads();
    }

    // epilogue: C = acc2 + b2 -> LDS (overlay U), then coalesced store + stats
#pragma unroll
    for (int i = 0; i < 4; ++i) {
#pragma unroll
        for (int u = 0; u < 2; ++u) {
            int c = cg * 4 + 128 * u;
            float4 bv = *(const float4*)&b2[c];
            float4 w;
            w.x = acc2[i][u * 4 + 0] + bv.x;
            w.y = acc2[i][u * 4 + 1] + bv.y;
            w.z = acc2[i][u * 4 + 2] + bv.z;
            w.w = acc2[i][u * 4 + 3] + bv.w;
            *(float4*)&C[(rg * 4 + i) * 264 + c] = w;
        }
    }
    __syncthreads();

    float s1 = 0.f, s2 = 0.f;
#pragma unroll
    for (int r = 0; r < 32; ++r) {
        float v = C[r * 264 + t];
        h2[(n0 + r) * 256 + t] = v;
        s1 += v;
        s2 += v * v;
    }
    int slot = blockIdx.x & 63;
    atomicAdd(&stats[slot * 512 + t], s1);
    atomicAdd(&stats[slot * 512 + 256 + t], s2);
}

// ---------------- BN finalize: scale/shift per feature ----------------
__global__ __launch_bounds__(256) void k_bn_finalize(
    float* __restrict__ scale, float* __restrict__ shift,
    const float* __restrict__ stats,
    const float* __restrict__ bn_g, const float* __restrict__ bn_b)
{
    int t = threadIdx.x;
    float s1 = 0.f, s2 = 0.f;
    for (int j = 0; j < 64; ++j) {
        s1 += stats[j * 512 + t];
        s2 += stats[j * 512 + 256 + t];
    }
    float mu  = s1 / (float)NN;
    float var = s2 / (float)NN - mu * mu;
    float sc  = bn_g[t] * rsqrtf(var + 1e-5f);
    scale[t] = sc;
    shift[t] = bn_b[t] - mu * sc;
}

// ---------------- normalize (+optional relu): h = act(h2*scale+shift) -----
template <int RELU>
__global__ __launch_bounds__(256) void k_norm(
    float4* __restrict__ h, const float4* __restrict__ h2,
    const float* __restrict__ scale, const float* __restrict__ shift)
{
    int idx = blockIdx.x * 256 + threadIdx.x;   // N*64 float4s
    int d4 = idx & 63;
    float4 v  = h2[idx];
    float4 sc = ((const float4*)scale)[d4];
    float4 sh = ((const float4*)shift)[d4];
    v.x = fmaf(v.x, sc.x, sh.x);
    v.y = fmaf(v.y, sc.y, sh.y);
    v.z = fmaf(v.z, sc.z, sh.z);
    v.w = fmaf(v.w, sc.w, sh.w);
    if (RELU) {
        v.x = fmaxf(v.x, 0.f); v.y = fmaxf(v.y, 0.f);
        v.z = fmaxf(v.z, 0.f); v.w = fmaxf(v.w, 0.f);
    }
    h[idx] = v;
}

// ---------------- mean-pool (sorted batch) + head MLP ----------------
__global__ __launch_bounds__(256) void k_pool_head(
    float* __restrict__ out, const float* __restrict__ h,
    const int* __restrict__ batch,
    const float* __restrict__ hW0, const float* __restrict__ hb0,
    const float* __restrict__ hW1, const float* __restrict__ hb1,
    const float* __restrict__ hW2, const float* __restrict__ hb2,
    const float* __restrict__ hW3, const float* __restrict__ hb3,
    const float* __restrict__ hWo, const float* __restrict__ hbo)
{
    int g = blockIdx.x;
    int t = threadIdx.x;

    int lo = 0, hi = NN;
    while (lo < hi) { int mid = (lo + hi) >> 1; if (batch[mid] < g) lo = mid + 1; else hi = mid; }
    int start = lo;
    hi = NN;
    while (lo < hi) { int mid = (lo + hi) >> 1; if (batch[mid] < g + 1) lo = mid + 1; else hi = mid; }
    int end = lo;

    float sum = 0.f;
    for (int n = start; n < end; ++n) sum += h[n * 256 + t];
    int cnt = end - start; if (cnt < 1) cnt = 1;

    __shared__ float za[256];
    __shared__ float zb[256];
    za[t] = sum / (float)cnt;
    __syncthreads();

    // L0: 256 -> 256
    {
        float a = hb0[t];
        for (int k = 0; k < 256; ++k) a = fmaf(za[k], hW0[k * 256 + t], a);
        zb[t] = fmaxf(a, 0.f);
    }
    __syncthreads();
    // L1: 256 -> 128
    float a1 = 0.f;
    if (t < 128) {
        a1 = hb1[t];
        for (int k = 0; k < 256; ++k) a1 = fmaf(zb[k], hW1[k * 128 + t], a1);
    }
    __syncthreads();
    if (t < 128) za[t] = fmaxf(a1, 0.f);
    __syncthreads();
    // L2: 128 -> 64
    float a2 = 0.f;
    if (t < 64) {
        a2 = hb2[t];
        for (int k = 0; k < 128; ++k) a2 = fmaf(za[k], hW2[k * 64 + t], a2);
    }
    __syncthreads();
    if (t < 64) zb[t] = fmaxf(a2, 0.f);
    __syncthreads();
    // L3: 64 -> 32
    float a3 = 0.f;
    if (t < 32) {
        a3 = hb3[t];
        for (int k = 0; k < 64; ++k) a3 = fmaf(zb[k], hW3[k * 32 + t], a3);
    }
    __syncthreads();
    if (t < 32) za[t] = fmaxf(a3, 0.f);
    __syncthreads();
    // out: 32 -> 1
    if (t == 0) {
        float s = hbo[0];
        for (int k = 0; k < 32; ++k) s = fmaf(za[k], hWo[k], s);
        out[g] = s;
    }
}

extern "C" void kernel_launch(void* const* d_in, const int* in_sizes, int n_in,
                              void* d_out, int out_size, void* d_ws, size_t ws_size,
                              hipStream_t stream)
{
    const float* x    = (const float*)d_in[0];
    const int*   ei   = (const int*)d_in[1];
    const int*   ea   = (const int*)d_in[2];
    const int*   batch= (const int*)d_in[3];
    const float* embW = (const float*)d_in[4];
    const float* embB = (const float*)d_in[5];
    const float* ee1  = (const float*)d_in[6];
    const float* ee2  = (const float*)d_in[7];
    const float* W1   = (const float*)d_in[8];
    const float* b1   = (const float*)d_in[9];
    const float* W2   = (const float*)d_in[10];
    const float* b2   = (const float*)d_in[11];
    const float* bng  = (const float*)d_in[12];
    const float* bnb  = (const float*)d_in[13];
    const float* hW0  = (const float*)d_in[14];
    const float* hb0  = (const float*)d_in[15];
    const float* hW1  = (const float*)d_in[16];
    const float* hb1  = (const float*)d_in[17];
    const float* hW2  = (const float*)d_in[18];
    const float* hb2  = (const float*)d_in[19];
    const float* hW3  = (const float*)d_in[20];
    const float* hb3  = (const float*)d_in[21];
    const float* hWo  = (const float*)d_in[22];
    const float* hbo  = (const float*)d_in[23];
    float* out = (float*)d_out;

    char* ws = (char*)d_ws;
    float* h     = (float*)ws;                                // N*256 f32
    float* agg   = (float*)(ws + (size_t)NN * 256 * 4);       // N*256 f32 (also h2)
    float* stats = (float*)(ws + (size_t)NN * 256 * 8);       // 64*512 f32
    float* scale = stats + 64 * 512;                          // 256
    float* shift = scale + 256;                               // 256

    k_embed<<<NN, 256, 0, stream>>>(h, x, embW, embB);

    for (int l = 0; l < LL; ++l) {
        const float* ee1l = ee1 + l * 6 * 256;
        const float* ee2l = ee2 + l * 3 * 256;
        hipMemsetAsync(stats, 0, 64 * 512 * 4, stream);
        k_init_agg<<<NN * 64 / 256, 256, 0, stream>>>((float4*)agg, (const float4*)h, ee1l, ee2l);
        k_scatter<<<EE, 256, 0, stream>>>(agg, h, ei, ea, ee1l, ee2l);
        k_fused_mlp<<<NN / 32, 256, 0, stream>>>(agg, agg,
                                                 W1 + (size_t)l * 256 * 512, b1 + l * 512,
                                                 W2 + (size_t)l * 512 * 256, b2 + l * 256, stats);
        k_bn_finalize<<<1, 256, 0, stream>>>(scale, shift, stats, bng + l * 256, bnb + l * 256);
        if (l < LL - 1)
            k_norm<1><<<NN * 64 / 256, 256, 0, stream>>>((float4*)h, (const float4*)agg, scale, shift);
        else
            k_norm<0><<<NN * 64 / 256, 256, 0, stream>>>((float4*)h, (const float4*)agg, scale, shift);
    }

    k_pool_head<<<GG, 256, 0, stream>>>(out, h, batch,
                                        hW0, hb0, hW1, hb1, hW2, hb2, hW3, hb3, hWo, hbo);
}

// Round 2
// 2652.151 us; speedup vs baseline: 2.6075x; 2.6075x over previous
//
#include <hip/hip_runtime.h>
#include <hip/hip_bf16.h>

#define NN 100000
#define EE 300000
#define GG 4000
#define LL 5

using bf16x8 = __attribute__((ext_vector_type(8))) short;
using f32x4  = __attribute__((ext_vector_type(4))) float;

__device__ inline short f2bf(float f) {
    unsigned u = __float_as_uint(f);
    u += 0x7FFFu + ((u >> 16) & 1u);
    return (short)(u >> 16);
}

__device__ inline int cvt_pk(float x, float y) {
    __hip_bfloat162 h = __float22bfloat162_rn(float2{x, y});
    int r; __builtin_memcpy(&r, &h, 4); return r;
}

__device__ inline void async_load16(const void* g, void* l) {
    __builtin_amdgcn_global_load_lds(
        (const __attribute__((address_space(1))) unsigned int*)g,
        (__attribute__((address_space(3))) unsigned int*)l, 16, 0, 0);
}

// ---------------- embed: h = relu(x @ embW + embB) ----------------
__global__ __launch_bounds__(256) void k_embed(
    float* __restrict__ h, const float* __restrict__ x,
    const float* __restrict__ embW, const float* __restrict__ embB)
{
    int n = blockIdx.x;
    int t = threadIdx.x;
    float acc = embB[t];
#pragma unroll
    for (int k = 0; k < 40; ++k)
        acc = fmaf(x[n * 40 + k], embW[k * 256 + t], acc);
    h[n * 256 + t] = fmaxf(acc, 0.f);
}

// ---------------- agg = h + ee1[l][4] + ee2[l][0] ----------------
__global__ __launch_bounds__(256) void k_init_agg(
    float4* __restrict__ agg, const float4* __restrict__ h,
    const float* __restrict__ ee1l, const float* __restrict__ ee2l)
{
    int idx = blockIdx.x * 256 + threadIdx.x;   // total N*64 float4s
    int d4 = idx & 63;
    const float* c1 = ee1l + 4 * 256;
    const float* c2 = ee2l;
    float4 hv = h[idx];
    float4 o;
    o.x = hv.x + c1[d4 * 4 + 0] + c2[d4 * 4 + 0];
    o.y = hv.y + c1[d4 * 4 + 1] + c2[d4 * 4 + 1];
    o.z = hv.z + c1[d4 * 4 + 2] + c2[d4 * 4 + 2];
    o.w = hv.w + c1[d4 * 4 + 3] + c2[d4 * 4 + 3];
    agg[idx] = o;
}

// ---------------- edge scatter: agg[dst] += h[src] + ee1[ea0] + ee2[ea1] ----
__global__ __launch_bounds__(256) void k_scatter(
    float* agg, const float* __restrict__ h,
    const int* __restrict__ edge_index, const int* __restrict__ edge_attr,
    const float* __restrict__ ee1l, const float* __restrict__ ee2l)
{
    int e = blockIdx.x;
    int t = threadIdx.x;
    int s  = edge_index[e];
    int d  = edge_index[EE + e];
    int a0 = edge_attr[2 * e];
    int a1 = edge_attr[2 * e + 1];
    float v = h[s * 256 + t] + ee1l[a0 * 256 + t] + ee2l[a1 * 256 + t];
    atomicAdd(&agg[d * 256 + t], v);
}

// ---------------- weight pack: dst[l][K/32][Nsz][32] bf16 <- src[l][K][Nsz] --
__global__ __launch_bounds__(256) void k_pack(
    short* __restrict__ dst, const float* __restrict__ src, int K, int Nsz)
{
    int nb = blockIdx.x, kb = blockIdx.y, l = blockIdx.z;
    int t = threadIdx.x;
    __shared__ float T[32][65];
    const float* s = src + ((size_t)l * K + kb * 32) * Nsz + nb * 64;
#pragma unroll
    for (int i = 0; i < 8; ++i) {
        int idx = i * 256 + t;
        int kk = idx >> 6, nl = idx & 63;
        T[kk][nl] = s[(size_t)kk * Nsz + nl];
    }
    __syncthreads();
    int nl = t >> 2, kq = t & 3;
    union { short s[8]; int4 v; } o;
#pragma unroll
    for (int j = 0; j < 8; ++j) o.s[j] = f2bf(T[kq * 8 + j][nl]);
    short* d = dst + (((size_t)l * (K / 32) + kb) * Nsz + nb * 64 + nl) * 32 + kq * 8;
    *(int4*)d = o.v;
}

// ---------------- GEMM1: U(bf16) = relu(agg_f32 @ W1p + b1) ----------------
// grid (782, 4); block 256 = 4 waves, each wave 64x64 of the 128x128 tile.
__global__ __launch_bounds__(256) void k_gemm1(
    short* __restrict__ U, const float* __restrict__ A,
    const short* __restrict__ Bp, const float* __restrict__ bias)
{
    __shared__ __align__(16) char smem[34816];
    float* As = (float*)smem;             // 128 x 32 f32 = 16KB
    short* Bs = (short*)(smem + 16384);   // 128 x 32 bf16 = 8KB
    short* Cs = (short*)smem;             // epilogue: 128 x 136 bf16 = 34816B

    const int t = threadIdx.x;
    const int w = t >> 6, lane = t & 63;
    const int quad = lane >> 4, l16 = lane & 15;
    const int wr = w >> 1, wc = w & 1;
    const int bm = blockIdx.x, bn = blockIdx.y;
    const int gm0 = bm * 128;

    float biasreg[4];
#pragma unroll
    for (int nt = 0; nt < 4; ++nt)
        biasreg[nt] = bias[bn * 128 + wc * 64 + nt * 16 + l16];

    f32x4 acc[4][4];
#pragma unroll
    for (int i = 0; i < 4; ++i)
#pragma unroll
        for (int j = 0; j < 4; ++j) acc[i][j] = (f32x4){0.f, 0.f, 0.f, 0.f};

    for (int kb = 0; kb < 8; ++kb) {
        __syncthreads();
        // stage A (fp32 128x32)
#pragma unroll
        for (int i = 0; i < 4; ++i) {
            int u = i * 256 + t;
            int m = u >> 3, ch = u & 7;
            int grow = gm0 + m; if (grow > NN - 1) grow = NN - 1;
            async_load16(A + (size_t)grow * 256 + kb * 32 + ch * 4, (char*)As + u * 16);
        }
        // stage B (bf16 128x32) from packed [kb][n][32]
#pragma unroll
        for (int i = 0; i < 2; ++i) {
            int u = i * 256 + t;
            int nl = u >> 2, ch = u & 3;
            async_load16(Bp + ((size_t)(kb * 512 + bn * 128 + nl)) * 32 + ch * 8,
                         (char*)Bs + u * 16);
        }
        __syncthreads();

        bf16x8 af[4], bfr[4];
#pragma unroll
        for (int mt = 0; mt < 4; ++mt) {
            int m = wr * 64 + mt * 16 + l16;
            const float* p = As + m * 32 + quad * 8;
            float4 p0 = *(const float4*)p;
            float4 p1 = *(const float4*)(p + 4);
            union { bf16x8 v; int i[4]; } uu;
            uu.i[0] = cvt_pk(p0.x, p0.y);
            uu.i[1] = cvt_pk(p0.z, p0.w);
            uu.i[2] = cvt_pk(p1.x, p1.y);
            uu.i[3] = cvt_pk(p1.z, p1.w);
            af[mt] = uu.v;
        }
#pragma unroll
        for (int nt = 0; nt < 4; ++nt) {
            int nl = wc * 64 + nt * 16 + l16;
            bfr[nt] = *(const bf16x8*)(Bs + nl * 32 + quad * 8);
        }
#pragma unroll
        for (int mt = 0; mt < 4; ++mt)
#pragma unroll
            for (int nt = 0; nt < 4; ++nt)
                acc[mt][nt] = __builtin_amdgcn_mfma_f32_16x16x32_bf16(
                    af[mt], bfr[nt], acc[mt][nt], 0, 0, 0);
    }

    __syncthreads();
    // epilogue: bias + relu -> bf16, LDS coalesce, masked store
#pragma unroll
    for (int mt = 0; mt < 4; ++mt)
#pragma unroll
        for (int nt = 0; nt < 4; ++nt)
#pragma unroll
            for (int r = 0; r < 4; ++r) {
                int row = wr * 64 + mt * 16 + quad * 4 + r;
                int col = wc * 64 + nt * 16 + l16;
                float v = acc[mt][nt][r] + biasreg[nt];
                Cs[row * 136 + col] = f2bf(fmaxf(v, 0.f));
            }
    __syncthreads();
#pragma unroll
    for (int i = 0; i < 8; ++i) {
        int u = i * 256 + t;
        int m = u >> 4, ch = u & 15;
        int grow = gm0 + m;
        if (grow < NN)
            *(int4*)(U + (size_t)grow * 512 + bn * 128 + ch * 8) =
                *(const int4*)(Cs + m * 136 + ch * 8);
    }
}

// ---------------- GEMM2: h2(f32) = U_bf16 @ W2p + b2, + BN stats ----------
// grid (782, 2)
__global__ __launch_bounds__(256) void k_gemm2(
    float* __restrict__ H2, const short* __restrict__ Uin,
    const short* __restrict__ Bp, const float* __restrict__ bias,
    float* __restrict__ stats)
{
    __shared__ __align__(16) char smem[33792];
    short* As = (short*)smem;             // 128 x 32 bf16 = 8KB
    short* Bs = (short*)(smem + 8192);    // 128 x 32 bf16 = 8KB
    float* Cf = (float*)smem;             // epilogue: 64 x 132 f32 = 33792B

    const int t = threadIdx.x;
    const int w = t >> 6, lane = t & 63;
    const int quad = lane >> 4, l16 = lane & 15;
    const int wr = w >> 1, wc = w & 1;
    const int bm = blockIdx.x, bn = blockIdx.y;
    const int gm0 = bm * 128;

    float biasreg[4];
#pragma unroll
    for (int nt = 0; nt < 4; ++nt)
        biasreg[nt] = bias[bn * 128 + wc * 64 + nt * 16 + l16];

    f32x4 acc[4][4];
#pragma unroll
    for (int i = 0; i < 4; ++i)
#pragma unroll
        for (int j = 0; j < 4; ++j) acc[i][j] = (f32x4){0.f, 0.f, 0.f, 0.f};

    for (int kb = 0; kb < 16; ++kb) {
        __syncthreads();
#pragma unroll
        for (int i = 0; i < 2; ++i) {
            int u = i * 256 + t;
            int m = u >> 2, ch = u & 3;
            int grow = gm0 + m; if (grow > NN - 1) grow = NN - 1;
            async_load16(Uin + (size_t)grow * 512 + kb * 32 + ch * 8, (char*)As + u * 16);
        }
#pragma unroll
        for (int i = 0; i < 2; ++i) {
            int u = i * 256 + t;
            int nl = u >> 2, ch = u & 3;
            async_load16(Bp + ((size_t)(kb * 256 + bn * 128 + nl)) * 32 + ch * 8,
                         (char*)Bs + u * 16);
        }
        __syncthreads();

        bf16x8 af[4], bfr[4];
#pragma unroll
        for (int mt = 0; mt < 4; ++mt) {
            int m = wr * 64 + mt * 16 + l16;
            af[mt] = *(const bf16x8*)(As + m * 32 + quad * 8);
        }
#pragma unroll
        for (int nt = 0; nt < 4; ++nt) {
            int nl = wc * 64 + nt * 16 + l16;
            bfr[nt] = *(const bf16x8*)(Bs + nl * 32 + quad * 8);
        }
#pragma unroll
        for (int mt = 0; mt < 4; ++mt)
#pragma unroll
            for (int nt = 0; nt < 4; ++nt)
                acc[mt][nt] = __builtin_amdgcn_mfma_f32_16x16x32_bf16(
                    af[mt], bfr[nt], acc[mt][nt], 0, 0, 0);
    }

    // BN partial stats from registers (masked for OOB rows)
    int slot = bm & 63;
#pragma unroll
    for (int nt = 0; nt < 4; ++nt) {
        float s1 = 0.f, s2 = 0.f;
#pragma unroll
        for (int mt = 0; mt < 4; ++mt)
#pragma unroll
            for (int r = 0; r < 4; ++r) {
                int grow = gm0 + wr * 64 + mt * 16 + quad * 4 + r;
                if (grow < NN) {
                    float v = acc[mt][nt][r] + biasreg[nt];
                    s1 += v; s2 += v * v;
                }
            }
        s1 += __shfl_xor(s1, 16, 64); s1 += __shfl_xor(s1, 32, 64);
        s2 += __shfl_xor(s2, 16, 64); s2 += __shfl_xor(s2, 32, 64);
        if (quad == 0) {
            int col = bn * 128 + wc * 64 + nt * 16 + l16;
            atomicAdd(&stats[slot * 512 + col], s1);
            atomicAdd(&stats[slot * 512 + 256 + col], s2);
        }
    }

    // store fp32 in two 64-row halves via LDS coalesce
#pragma unroll
    for (int h = 0; h < 2; ++h) {
        __syncthreads();
        if (wr == h) {
#pragma unroll
            for (int mt = 0; mt < 4; ++mt)
#pragma unroll
                for (int nt = 0; nt < 4; ++nt)
#pragma unroll
                    for (int r = 0; r < 4; ++r) {
                        int rl = mt * 16 + quad * 4 + r;
                        int col = wc * 64 + nt * 16 + l16;
                        Cf[rl * 132 + col] = acc[mt][nt][r] + biasreg[nt];
                    }
        }
        __syncthreads();
#pragma unroll
        for (int i = 0; i < 8; ++i) {
            int u = i * 256 + t;
            int m = u >> 5, ch = u & 31;
            int grow = gm0 + h * 64 + m;
            if (grow < NN)
                *(float4*)(H2 + (size_t)grow * 256 + bn * 128 + ch * 4) =
                    *(const float4*)(Cf + m * 132 + ch * 4);
        }
    }
}

// ---------------- BN finalize ----------------
__global__ __launch_bounds__(256) void k_bn_finalize(
    float* __restrict__ scale, float* __restrict__ shift,
    const float* __restrict__ stats,
    const float* __restrict__ bn_g, const float* __restrict__ bn_b)
{
    int t = threadIdx.x;
    float s1 = 0.f, s2 = 0.f;
    for (int j = 0; j < 64; ++j) {
        s1 += stats[j * 512 + t];
        s2 += stats[j * 512 + 256 + t];
    }
    float mu  = s1 / (float)NN;
    float var = s2 / (float)NN - mu * mu;
    float sc  = bn_g[t] * rsqrtf(var + 1e-5f);
    scale[t] = sc;
    shift[t] = bn_b[t] - mu * sc;
}

// ---------------- normalize (+optional relu) ----------------
template <int RELU>
__global__ __launch_bounds__(256) void k_norm(
    float4* __restrict__ h, const float4* __restrict__ h2,
    const float* __restrict__ scale, const float* __restrict__ shift)
{
    int idx = blockIdx.x * 256 + threadIdx.x;
    int d4 = idx & 63;
    float4 v  = h2[idx];
    float4 sc = ((const float4*)scale)[d4];
    float4 sh = ((const float4*)shift)[d4];
    v.x = fmaf(v.x, sc.x, sh.x);
    v.y = fmaf(v.y, sc.y, sh.y);
    v.z = fmaf(v.z, sc.z, sh.z);
    v.w = fmaf(v.w, sc.w, sh.w);
    if (RELU) {
        v.x = fmaxf(v.x, 0.f); v.y = fmaxf(v.y, 0.f);
        v.z = fmaxf(v.z, 0.f); v.w = fmaxf(v.w, 0.f);
    }
    h[idx] = v;
}

// ---------------- mean-pool (sorted batch) + head MLP ----------------
__global__ __launch_bounds__(256) void k_pool_head(
    float* __restrict__ out, const float* __restrict__ h,
    const int* __restrict__ batch,
    const float* __restrict__ hW0, const float* __restrict__ hb0,
    const float* __restrict__ hW1, const float* __restrict__ hb1,
    const float* __restrict__ hW2, const float* __restrict__ hb2,
    const float* __restrict__ hW3, const float* __restrict__ hb3,
    const float* __restrict__ hWo, const float* __restrict__ hbo)
{
    int g = blockIdx.x;
    int t = threadIdx.x;

    int lo = 0, hi = NN;
    while (lo < hi) { int mid = (lo + hi) >> 1; if (batch[mid] < g) lo = mid + 1; else hi = mid; }
    int start = lo;
    hi = NN;
    while (lo < hi) { int mid = (lo + hi) >> 1; if (batch[mid] < g + 1) lo = mid + 1; else hi = mid; }
    int end = lo;

    float sum = 0.f;
    for (int n = start; n < end; ++n) sum += h[n * 256 + t];
    int cnt = end - start; if (cnt < 1) cnt = 1;

    __shared__ float za[256];
    __shared__ float zb[256];
    za[t] = sum / (float)cnt;
    __syncthreads();

    {
        float a = hb0[t];
        for (int k = 0; k < 256; ++k) a = fmaf(za[k], hW0[k * 256 + t], a);
        zb[t] = fmaxf(a, 0.f);
    }
    __syncthreads();
    float a1 = 0.f;
    if (t < 128) {
        a1 = hb1[t];
        for (int k = 0; k < 256; ++k) a1 = fmaf(zb[k], hW1[k * 128 + t], a1);
    }
    __syncthreads();
    if (t < 128) za[t] = fmaxf(a1, 0.f);
    __syncthreads();
    float a2 = 0.f;
    if (t < 64) {
        a2 = hb2[t];
        for (int k = 0; k < 128; ++k) a2 = fmaf(za[k], hW2[k * 64 + t], a2);
    }
    __syncthreads();
    if (t < 64) zb[t] = fmaxf(a2, 0.f);
    __syncthreads();
    float a3 = 0.f;
    if (t < 32) {
        a3 = hb3[t];
        for (int k = 0; k < 64; ++k) a3 = fmaf(zb[k], hW3[k * 32 + t], a3);
    }
    __syncthreads();
    if (t < 32) za[t] = fmaxf(a3, 0.f);
    __syncthreads();
    if (t == 0) {
        float s = hbo[0];
        for (int k = 0; k < 32; ++k) s = fmaf(za[k], hWo[k], s);
        out[g] = s;
    }
}

extern "C" void kernel_launch(void* const* d_in, const int* in_sizes, int n_in,
                              void* d_out, int out_size, void* d_ws, size_t ws_size,
                              hipStream_t stream)
{
    const float* x    = (const float*)d_in[0];
    const int*   ei   = (const int*)d_in[1];
    const int*   ea   = (const int*)d_in[2];
    const int*   batch= (const int*)d_in[3];
    const float* embW = (const float*)d_in[4];
    const float* embB = (const float*)d_in[5];
    const float* ee1  = (const float*)d_in[6];
    const float* ee2  = (const float*)d_in[7];
    const float* W1   = (const float*)d_in[8];
    const float* b1   = (const float*)d_in[9];
    const float* W2   = (const float*)d_in[10];
    const float* b2   = (const float*)d_in[11];
    const float* bng  = (const float*)d_in[12];
    const float* bnb  = (const float*)d_in[13];
    const float* hW0  = (const float*)d_in[14];
    const float* hb0  = (const float*)d_in[15];
    const float* hW1  = (const float*)d_in[16];
    const float* hb1  = (const float*)d_in[17];
    const float* hW2  = (const float*)d_in[18];
    const float* hb2  = (const float*)d_in[19];
    const float* hW3  = (const float*)d_in[20];
    const float* hb3  = (const float*)d_in[21];
    const float* hWo  = (const float*)d_in[22];
    const float* hbo  = (const float*)d_in[23];
    float* out = (float*)d_out;

    const size_t BUF = (size_t)NN * 256 * 4;   // 102,400,000 B
    char* ws = (char*)d_ws;
    float* buf1  = (float*)ws;                         // h / U(bf16) / h
    float* buf2  = (float*)(ws + BUF);                 // agg / h2
    float* stats = (float*)(ws + 2 * BUF);             // 64*512 f32
    float* scale = stats + 64 * 512;
    float* shift = scale + 256;
    short* W1p   = (short*)(shift + 256);              // 5 * 131072 bf16
    short* W2p   = W1p + 5 * 131072;                   // 5 * 131072 bf16

    // pack weights (every call; graph-safe)
    k_pack<<<dim3(8, 8, 5), 256, 0, stream>>>(W1p, W1, 256, 512);
    k_pack<<<dim3(4, 16, 5), 256, 0, stream>>>(W2p, W2, 512, 256);

    k_embed<<<NN, 256, 0, stream>>>(buf1, x, embW, embB);

    for (int l = 0; l < LL; ++l) {
        const float* ee1l = ee1 + l * 6 * 256;
        const float* ee2l = ee2 + l * 3 * 256;
        hipMemsetAsync(stats, 0, 64 * 512 * 4, stream);
        k_init_agg<<<NN * 64 / 256, 256, 0, stream>>>((float4*)buf2, (const float4*)buf1, ee1l, ee2l);
        k_scatter<<<EE, 256, 0, stream>>>(buf2, buf1, ei, ea, ee1l, ee2l);
        k_gemm1<<<dim3(782, 4), 256, 0, stream>>>((short*)buf1, buf2,
                                                  W1p + (size_t)l * 131072, b1 + l * 512);
        k_gemm2<<<dim3(782, 2), 256, 0, stream>>>(buf2, (const short*)buf1,
                                                  W2p + (size_t)l * 131072, b2 + l * 256, stats);
        k_bn_finalize<<<1, 256, 0, stream>>>(scale, shift, stats, bng + l * 256, bnb + l * 256);
        if (l < LL - 1)
            k_norm<1><<<NN * 64 / 256, 256, 0, stream>>>((float4*)buf1, (const float4*)buf2, scale, shift);
        else
            k_norm<0><<<NN * 64 / 256, 256, 0, stream>>>((float4*)buf1, (const float4*)buf2, scale, shift);
    }

    k_pool_head<<<GG, 256, 0, stream>>>(out, buf1, batch,
                                        hW0, hb0, hW1, hb1, hW2, hb2, hW3, hb3, hWo, hbo);
}

// Round 3
// 1350.418 us; speedup vs baseline: 5.1211x; 1.9639x over previous
//
#include <hip/hip_runtime.h>
#include <hip/hip_bf16.h>

#define NN 100000
#define EE 300000
#define GG 4000
#define LL 5

typedef _Float16 half8  __attribute__((ext_vector_type(8)));
typedef _Float16 half4v __attribute__((ext_vector_type(4)));
typedef float    f32x4  __attribute__((ext_vector_type(4)));

__device__ inline short f2h(float f) {
    _Float16 h = (_Float16)f;
    short s; __builtin_memcpy(&s, &h, 2); return s;
}

__device__ inline void async_load16(const void* g, void* l) {
    __builtin_amdgcn_global_load_lds(
        (const __attribute__((address_space(1))) unsigned int*)g,
        (__attribute__((address_space(3))) unsigned int*)l, 16, 0, 0);
}

// ---------------- embed: h = relu(x @ embW + embB) -> fp16 ----------------
__global__ __launch_bounds__(256) void k_embed(
    _Float16* __restrict__ h, const float* __restrict__ x,
    const float* __restrict__ embW, const float* __restrict__ embB)
{
    int n = blockIdx.x;
    int t = threadIdx.x;
    float acc = embB[t];
#pragma unroll
    for (int k = 0; k < 40; ++k)
        acc = fmaf(x[n * 40 + k], embW[k * 256 + t], acc);
    h[n * 256 + t] = (_Float16)fmaxf(acc, 0.f);
}

// ---------------- CSR build ----------------
__global__ __launch_bounds__(256) void k_count(
    int* __restrict__ deg, const int* __restrict__ ei)
{
    int e = blockIdx.x * 256 + threadIdx.x;
    if (e < EE) atomicAdd(&deg[ei[EE + e]], 1);
}

__global__ __launch_bounds__(1024) void k_scan(
    int* __restrict__ offs, int* __restrict__ cursor, const int* __restrict__ deg)
{
    __shared__ int wsum[16];
    __shared__ int sbase;
    int t = threadIdx.x;
    int lane = t & 63, w = t >> 6;
    if (t == 0) sbase = 0;
    __syncthreads();
    for (int base = 0; base < NN; base += 1024) {
        int v = (base + t < NN) ? deg[base + t] : 0;
        int x = v;
#pragma unroll
        for (int off = 1; off < 64; off <<= 1) {
            int nb = __shfl_up(x, off, 64);
            if (lane >= off) x += nb;
        }
        if (lane == 63) wsum[w] = x;
        __syncthreads();
        if (w == 0 && lane < 16) {
            int s = wsum[lane];
#pragma unroll
            for (int off = 1; off < 16; off <<= 1) {
                int nb = __shfl_up(s, off, 64);
                if (lane >= off) s += nb;
            }
            wsum[lane] = s;
        }
        __syncthreads();
        int add = (w > 0) ? wsum[w - 1] : 0;
        int total = wsum[15];
        int excl = sbase + add + x - v;
        if (base + t < NN) { offs[base + t] = excl; cursor[base + t] = excl; }
        __syncthreads();
        if (t == 0) sbase += total;
        __syncthreads();
    }
    if (t == 0) offs[NN] = sbase;
}

__global__ __launch_bounds__(256) void k_fill(
    int* __restrict__ csr, int* __restrict__ cursor,
    const int* __restrict__ ei, const int* __restrict__ ea)
{
    int e = blockIdx.x * 256 + threadIdx.x;
    if (e >= EE) return;
    int s = ei[e];
    int d = ei[EE + e];
    int c = ea[2 * e] * 3 + ea[2 * e + 1];
    int slot = atomicAdd(&cursor[d], 1);
    csr[slot] = s | (c << 20);
}

// ---------------- combo tables: tbl[l][c][256], c=9 is const row ----------
__global__ __launch_bounds__(256) void k_combo(
    float* __restrict__ tbl, const float* __restrict__ ee1, const float* __restrict__ ee2)
{
    int c = blockIdx.x;   // 0..9
    int l = blockIdx.y;   // 0..4
    int t = threadIdx.x;
    int i1 = (c < 9) ? c / 3 : 4;
    int i2 = (c < 9) ? c % 3 : 0;
    tbl[((size_t)l * 10 + c) * 256 + t] =
        ee1[((size_t)l * 6 + i1) * 256 + t] + ee2[((size_t)l * 3 + i2) * 256 + t];
}

// ---------------- identity affine init ----------------
__global__ __launch_bounds__(256) void k_init_id(
    float* __restrict__ scale, float* __restrict__ shift)
{
    int t = threadIdx.x;
    scale[t] = 1.f;
    shift[t] = 0.f;
}

// ---------------- fused aggregate ----------------
// agg[n] = act(aff(h[n])) + tbl[9] + sum_e( act(aff(h[src_e])) + tbl[c_e] )
// act = relu (input is always a post-relu tensor or gets relu in reference).
// one wave per node; lane handles 4 dims.
__global__ __launch_bounds__(256) void k_aggregate(
    _Float16* __restrict__ agg, const _Float16* __restrict__ hin,
    const int* __restrict__ offs, const int* __restrict__ csr,
    const float* __restrict__ tbl,        // this layer's [10][256]
    const float* __restrict__ scale, const float* __restrict__ shift)
{
    int t = threadIdx.x;
    int w = t >> 6, lane = t & 63;
    int n = blockIdx.x * 4 + w;

    const f32x4 sc = ((const f32x4*)scale)[lane];
    const f32x4 sh = ((const f32x4*)shift)[lane];
    const f32x4* tb4 = (const f32x4*)tbl;

    // own row + const row
    half4v hv = *(const half4v*)(hin + (size_t)n * 256 + lane * 4);
    f32x4 acc = tb4[9 * 64 + lane];
#pragma unroll
    for (int i = 0; i < 4; ++i)
        acc[i] += fmaxf(fmaf((float)hv[i], sc[i], sh[i]), 0.f);

    int o0 = offs[n], o1 = offs[n + 1];
    for (int j = o0; j < o1; ++j) {
        int entry = csr[j];
        int s = entry & 0xFFFFF;
        int c = entry >> 20;
        half4v gv = *(const half4v*)(hin + (size_t)s * 256 + lane * 4);
        f32x4 tv = tb4[c * 64 + lane];
#pragma unroll
        for (int i = 0; i < 4; ++i)
            acc[i] += fmaxf(fmaf((float)gv[i], sc[i], sh[i]), 0.f) + tv[i];
    }

    half4v o;
#pragma unroll
    for (int i = 0; i < 4; ++i) o[i] = (_Float16)acc[i];
    *(half4v*)(agg + (size_t)n * 256 + lane * 4) = o;
}

// ---------------- weight pack: dst[l][K/32][Nsz][32] f16 <- src[l][K][Nsz] --
__global__ __launch_bounds__(256) void k_pack(
    short* __restrict__ dst, const float* __restrict__ src, int K, int Nsz)
{
    int nb = blockIdx.x, kb = blockIdx.y, l = blockIdx.z;
    int t = threadIdx.x;
    __shared__ float T[32][65];
    const float* s = src + ((size_t)l * K + kb * 32) * Nsz + nb * 64;
#pragma unroll
    for (int i = 0; i < 8; ++i) {
        int idx = i * 256 + t;
        int kk = idx >> 6, nl = idx & 63;
        T[kk][nl] = s[(size_t)kk * Nsz + nl];
    }
    __syncthreads();
    int nl = t >> 2, kq = t & 3;
    union { short s[8]; int4 v; } o;
#pragma unroll
    for (int j = 0; j < 8; ++j) o.s[j] = f2h(T[kq * 8 + j][nl]);
    short* d = dst + (((size_t)l * (K / 32) + kb) * Nsz + nb * 64 + nl) * 32 + kq * 8;
    *(int4*)d = o.v;
}

// ---------------- GEMM1: U(f16) = relu(agg_f16 @ W1p + b1), grid(782,4) ----
__global__ __launch_bounds__(256) void k_gemm1(
    _Float16* __restrict__ U, const _Float16* __restrict__ A,
    const short* __restrict__ Bp, const float* __restrict__ bias)
{
    __shared__ __align__(16) char smem[34816];
    _Float16* As = (_Float16*)smem;            // 128 x 32
    _Float16* Bs = (_Float16*)(smem + 8192);   // 128 x 32
    _Float16* Cs = (_Float16*)smem;            // 128 x 136 epilogue

    const int t = threadIdx.x;
    const int w = t >> 6, lane = t & 63;
    const int quad = lane >> 4, l16 = lane & 15;
    const int wr = w >> 1, wc = w & 1;
    const int bm = blockIdx.x, bn = blockIdx.y;
    const int gm0 = bm * 128;

    float biasreg[4];
#pragma unroll
    for (int nt = 0; nt < 4; ++nt)
        biasreg[nt] = bias[bn * 128 + wc * 64 + nt * 16 + l16];

    f32x4 acc[4][4];
#pragma unroll
    for (int i = 0; i < 4; ++i)
#pragma unroll
        for (int j = 0; j < 4; ++j) acc[i][j] = (f32x4){0.f, 0.f, 0.f, 0.f};

    for (int kb = 0; kb < 8; ++kb) {
        __syncthreads();
#pragma unroll
        for (int i = 0; i < 2; ++i) {
            int u = i * 256 + t;
            int m = u >> 2, ch = u & 3;
            int grow = gm0 + m; if (grow > NN - 1) grow = NN - 1;
            async_load16(A + (size_t)grow * 256 + kb * 32 + ch * 8, (char*)As + u * 16);
        }
#pragma unroll
        for (int i = 0; i < 2; ++i) {
            int u = i * 256 + t;
            int nl = u >> 2, ch = u & 3;
            async_load16(Bp + ((size_t)(kb * 512 + bn * 128 + nl)) * 32 + ch * 8,
                         (char*)Bs + u * 16);
        }
        __syncthreads();

        half8 af[4], bfr[4];
#pragma unroll
        for (int mt = 0; mt < 4; ++mt)
            af[mt] = *(const half8*)(As + (wr * 64 + mt * 16 + l16) * 32 + quad * 8);
#pragma unroll
        for (int nt = 0; nt < 4; ++nt)
            bfr[nt] = *(const half8*)(Bs + (wc * 64 + nt * 16 + l16) * 32 + quad * 8);
#pragma unroll
        for (int mt = 0; mt < 4; ++mt)
#pragma unroll
            for (int nt = 0; nt < 4; ++nt)
                acc[mt][nt] = __builtin_amdgcn_mfma_f32_16x16x32_f16(
                    af[mt], bfr[nt], acc[mt][nt], 0, 0, 0);
    }

    __syncthreads();
#pragma unroll
    for (int mt = 0; mt < 4; ++mt)
#pragma unroll
        for (int nt = 0; nt < 4; ++nt)
#pragma unroll
            for (int r = 0; r < 4; ++r) {
                int row = wr * 64 + mt * 16 + quad * 4 + r;
                int col = wc * 64 + nt * 16 + l16;
                Cs[row * 136 + col] = (_Float16)fmaxf(acc[mt][nt][r] + biasreg[nt], 0.f);
            }
    __syncthreads();
#pragma unroll
    for (int i = 0; i < 8; ++i) {
        int u = i * 256 + t;
        int m = u >> 4, ch = u & 15;
        int grow = gm0 + m;
        if (grow < NN)
            *(int4*)(U + (size_t)grow * 512 + bn * 128 + ch * 8) =
                *(const int4*)(Cs + m * 136 + ch * 8);
    }
}

// ---------------- GEMM2: h2(f16) = U @ W2p + b2, + BN stats, grid(782,2) --
__global__ __launch_bounds__(256) void k_gemm2(
    _Float16* __restrict__ H2, const _Float16* __restrict__ Uin,
    const short* __restrict__ Bp, const float* __restrict__ bias,
    float* __restrict__ stats)
{
    __shared__ __align__(16) char smem[34816];
    _Float16* As = (_Float16*)smem;
    _Float16* Bs = (_Float16*)(smem + 8192);
    _Float16* Cs = (_Float16*)smem;

    const int t = threadIdx.x;
    const int w = t >> 6, lane = t & 63;
    const int quad = lane >> 4, l16 = lane & 15;
    const int wr = w >> 1, wc = w & 1;
    const int bm = blockIdx.x, bn = blockIdx.y;
    const int gm0 = bm * 128;

    float biasreg[4];
#pragma unroll
    for (int nt = 0; nt < 4; ++nt)
        biasreg[nt] = bias[bn * 128 + wc * 64 + nt * 16 + l16];

    f32x4 acc[4][4];
#pragma unroll
    for (int i = 0; i < 4; ++i)
#pragma unroll
        for (int j = 0; j < 4; ++j) acc[i][j] = (f32x4){0.f, 0.f, 0.f, 0.f};

    for (int kb = 0; kb < 16; ++kb) {
        __syncthreads();
#pragma unroll
        for (int i = 0; i < 2; ++i) {
            int u = i * 256 + t;
            int m = u >> 2, ch = u & 3;
            int grow = gm0 + m; if (grow > NN - 1) grow = NN - 1;
            async_load16(Uin + (size_t)grow * 512 + kb * 32 + ch * 8, (char*)As + u * 16);
        }
#pragma unroll
        for (int i = 0; i < 2; ++i) {
            int u = i * 256 + t;
            int nl = u >> 2, ch = u & 3;
            async_load16(Bp + ((size_t)(kb * 256 + bn * 128 + nl)) * 32 + ch * 8,
                         (char*)Bs + u * 16);
        }
        __syncthreads();

        half8 af[4], bfr[4];
#pragma unroll
        for (int mt = 0; mt < 4; ++mt)
            af[mt] = *(const half8*)(As + (wr * 64 + mt * 16 + l16) * 32 + quad * 8);
#pragma unroll
        for (int nt = 0; nt < 4; ++nt)
            bfr[nt] = *(const half8*)(Bs + (wc * 64 + nt * 16 + l16) * 32 + quad * 8);
#pragma unroll
        for (int mt = 0; mt < 4; ++mt)
#pragma unroll
            for (int nt = 0; nt < 4; ++nt)
                acc[mt][nt] = __builtin_amdgcn_mfma_f32_16x16x32_f16(
                    af[mt], bfr[nt], acc[mt][nt], 0, 0, 0);
    }

    // BN partial stats (fp32, masked OOB rows)
    int slot = bm & 63;
#pragma unroll
    for (int nt = 0; nt < 4; ++nt) {
        float s1 = 0.f, s2 = 0.f;
#pragma unroll
        for (int mt = 0; mt < 4; ++mt)
#pragma unroll
            for (int r = 0; r < 4; ++r) {
                int grow = gm0 + wr * 64 + mt * 16 + quad * 4 + r;
                if (grow < NN) {
                    float v = acc[mt][nt][r] + biasreg[nt];
                    s1 += v; s2 += v * v;
                }
            }
        s1 += __shfl_xor(s1, 16, 64); s1 += __shfl_xor(s1, 32, 64);
        s2 += __shfl_xor(s2, 16, 64); s2 += __shfl_xor(s2, 32, 64);
        if (quad == 0) {
            int col = bn * 128 + wc * 64 + nt * 16 + l16;
            atomicAdd(&stats[slot * 512 + col], s1);
            atomicAdd(&stats[slot * 512 + 256 + col], s2);
        }
    }

    __syncthreads();
#pragma unroll
    for (int mt = 0; mt < 4; ++mt)
#pragma unroll
        for (int nt = 0; nt < 4; ++nt)
#pragma unroll
            for (int r = 0; r < 4; ++r) {
                int row = wr * 64 + mt * 16 + quad * 4 + r;
                int col = wc * 64 + nt * 16 + l16;
                Cs[row * 136 + col] = (_Float16)(acc[mt][nt][r] + biasreg[nt]);
            }
    __syncthreads();
#pragma unroll
    for (int i = 0; i < 8; ++i) {
        int u = i * 256 + t;
        int m = u >> 4, ch = u & 15;
        int grow = gm0 + m;
        if (grow < NN)
            *(int4*)(H2 + (size_t)grow * 256 + bn * 128 + ch * 8) =
                *(const int4*)(Cs + m * 136 + ch * 8);
    }
}

// ---------------- BN finalize ----------------
__global__ __launch_bounds__(256) void k_bn_finalize(
    float* __restrict__ scale, float* __restrict__ shift,
    const float* __restrict__ stats,
    const float* __restrict__ bn_g, const float* __restrict__ bn_b)
{
    int t = threadIdx.x;
    float s1 = 0.f, s2 = 0.f;
    for (int j = 0; j < 64; ++j) {
        s1 += stats[j * 512 + t];
        s2 += stats[j * 512 + 256 + t];
    }
    float mu  = s1 / (float)NN;
    float var = s2 / (float)NN - mu * mu;
    float sc  = bn_g[t] * rsqrtf(var + 1e-5f);
    scale[t] = sc;
    shift[t] = bn_b[t] - mu * sc;
}

// ---------------- mean-pool + affine + head MLP ----------------
__global__ __launch_bounds__(256) void k_pool_head(
    float* __restrict__ out, const _Float16* __restrict__ h,
    const int* __restrict__ batch,
    const float* __restrict__ scale, const float* __restrict__ shift,
    const float* __restrict__ hW0, const float* __restrict__ hb0,
    const float* __restrict__ hW1, const float* __restrict__ hb1,
    const float* __restrict__ hW2, const float* __restrict__ hb2,
    const float* __restrict__ hW3, const float* __restrict__ hb3,
    const float* __restrict__ hWo, const float* __restrict__ hbo)
{
    int g = blockIdx.x;
    int t = threadIdx.x;

    int lo = 0, hi = NN;
    while (lo < hi) { int mid = (lo + hi) >> 1; if (batch[mid] < g) lo = mid + 1; else hi = mid; }
    int start = lo;
    hi = NN;
    while (lo < hi) { int mid = (lo + hi) >> 1; if (batch[mid] < g + 1) lo = mid + 1; else hi = mid; }
    int end = lo;

    float sum = 0.f;
    for (int n = start; n < end; ++n) sum += (float)h[(size_t)n * 256 + t];
    int cnt = end - start; if (cnt < 1) cnt = 1;

    __shared__ float za[256];
    __shared__ float zb[256];
    za[t] = fmaf(sum / (float)cnt, scale[t], shift[t]);
    __syncthreads();

    {
        float a = hb0[t];
        for (int k = 0; k < 256; ++k) a = fmaf(za[k], hW0[k * 256 + t], a);
        zb[t] = fmaxf(a, 0.f);
    }
    __syncthreads();
    float a1 = 0.f;
    if (t < 128) {
        a1 = hb1[t];
        for (int k = 0; k < 256; ++k) a1 = fmaf(zb[k], hW1[k * 128 + t], a1);
    }
    __syncthreads();
    if (t < 128) za[t] = fmaxf(a1, 0.f);
    __syncthreads();
    float a2 = 0.f;
    if (t < 64) {
        a2 = hb2[t];
        for (int k = 0; k < 128; ++k) a2 = fmaf(za[k], hW2[k * 64 + t], a2);
    }
    __syncthreads();
    if (t < 64) zb[t] = fmaxf(a2, 0.f);
    __syncthreads();
    float a3 = 0.f;
    if (t < 32) {
        a3 = hb3[t];
        for (int k = 0; k < 64; ++k) a3 = fmaf(zb[k], hW3[k * 32 + t], a3);
    }
    __syncthreads();
    if (t < 32) za[t] = fmaxf(a3, 0.f);
    __syncthreads();
    if (t == 0) {
        float s = hbo[0];
        for (int k = 0; k < 32; ++k) s = fmaf(za[k], hWo[k], s);
        out[g] = s;
    }
}

extern "C" void kernel_launch(void* const* d_in, const int* in_sizes, int n_in,
                              void* d_out, int out_size, void* d_ws, size_t ws_size,
                              hipStream_t stream)
{
    const float* x    = (const float*)d_in[0];
    const int*   ei   = (const int*)d_in[1];
    const int*   ea   = (const int*)d_in[2];
    const int*   batch= (const int*)d_in[3];
    const float* embW = (const float*)d_in[4];
    const float* embB = (const float*)d_in[5];
    const float* ee1  = (const float*)d_in[6];
    const float* ee2  = (const float*)d_in[7];
    const float* W1   = (const float*)d_in[8];
    const float* b1   = (const float*)d_in[9];
    const float* W2   = (const float*)d_in[10];
    const float* b2   = (const float*)d_in[11];
    const float* bng  = (const float*)d_in[12];
    const float* bnb  = (const float*)d_in[13];
    const float* hW0  = (const float*)d_in[14];
    const float* hb0  = (const float*)d_in[15];
    const float* hW1  = (const float*)d_in[16];
    const float* hb1  = (const float*)d_in[17];
    const float* hW2  = (const float*)d_in[18];
    const float* hb2  = (const float*)d_in[19];
    const float* hW3  = (const float*)d_in[20];
    const float* hb3  = (const float*)d_in[21];
    const float* hWo  = (const float*)d_in[22];
    const float* hbo  = (const float*)d_in[23];
    float* out = (float*)d_out;

    char* ws = (char*)d_ws;
    size_t off = 0;
    _Float16* h2buf = (_Float16*)(ws + off); off += (size_t)NN * 256 * 2;   // 51.2 MB (embed out / h2)
    _Float16* aggbuf= (_Float16*)(ws + off); off += (size_t)NN * 256 * 2;   // 51.2 MB
    _Float16* Ubuf  = (_Float16*)(ws + off); off += (size_t)NN * 512 * 2;   // 102.4 MB
    short* W1p      = (short*)(ws + off);    off += (size_t)5 * 131072 * 2;
    short* W2p      = (short*)(ws + off);    off += (size_t)5 * 131072 * 2;
    float* tbl      = (float*)(ws + off);    off += (size_t)5 * 10 * 256 * 4;
    float* stats    = (float*)(ws + off);    off += (size_t)64 * 512 * 4;
    float* scale    = (float*)(ws + off);    off += 256 * 4;
    float* shift    = (float*)(ws + off);    off += 256 * 4;
    int* deg        = (int*)(ws + off);      off += (size_t)NN * 4;
    int* offs       = (int*)(ws + off);      off += (size_t)(NN + 1) * 4;
    int* cursor     = (int*)(ws + off);      off += (size_t)NN * 4;
    int* csr        = (int*)(ws + off);      off += (size_t)EE * 4;

    // ---- one-time per call: CSR + tables + packs + identity affine ----
    hipMemsetAsync(deg, 0, (size_t)NN * 4, stream);
    k_count<<<(EE + 255) / 256, 256, 0, stream>>>(deg, ei);
    k_scan<<<1, 1024, 0, stream>>>(offs, cursor, deg);
    k_fill<<<(EE + 255) / 256, 256, 0, stream>>>(csr, cursor, ei, ea);
    k_combo<<<dim3(10, 5), 256, 0, stream>>>(tbl, ee1, ee2);
    k_pack<<<dim3(8, 8, 5), 256, 0, stream>>>(W1p, W1, 256, 512);
    k_pack<<<dim3(4, 16, 5), 256, 0, stream>>>(W2p, W2, 512, 256);
    k_init_id<<<1, 256, 0, stream>>>(scale, shift);

    k_embed<<<NN, 256, 0, stream>>>(h2buf, x, embW, embB);

    for (int l = 0; l < LL; ++l) {
        hipMemsetAsync(stats, 0, (size_t)64 * 512 * 4, stream);
        k_aggregate<<<NN / 4, 256, 0, stream>>>(aggbuf, h2buf, offs, csr,
                                                tbl + (size_t)l * 10 * 256, scale, shift);
        k_gemm1<<<dim3(782, 4), 256, 0, stream>>>(Ubuf, aggbuf,
                                                  W1p + (size_t)l * 131072, b1 + l * 512);
        k_gemm2<<<dim3(782, 2), 256, 0, stream>>>(h2buf, Ubuf,
                                                  W2p + (size_t)l * 131072, b2 + l * 256, stats);
        k_bn_finalize<<<1, 256, 0, stream>>>(scale, shift, stats, bng + l * 256, bnb + l * 256);
    }

    k_pool_head<<<GG, 256, 0, stream>>>(out, h2buf, batch, scale, shift,
                                        hW0, hb0, hW1, hb1, hW2, hb2, hW3, hb3, hWo, hbo);
}